// Round 6
// baseline (587.346 us; speedup 1.0000x reference)
//
#include <hip/hip_runtime.h>
#include <hip/hip_cooperative_groups.h>

namespace cg = cooperative_groups;

#define NB 16
#define NEV 960000
#define NS 48
#define SEG 20000
#define S_IDX 3
#define E_IDX 38
#define N_ITER 34
#define ND 256
#define NCH 35          // chunks S_IDX .. E_IDX-1
#define GRID 512        // fused-kernel grid (2 blocks/CU on 256 CUs)

// ---------------- shared helpers -------------------------------------------
__device__ inline float median10(const float* v) {
    float w[10];
    #pragma unroll
    for (int i = 0; i < 10; i++) w[i] = v[i];
    #pragma unroll
    for (int i = 1; i < 10; i++) {
        float k = w[i]; int j = i - 1;
        while (j >= 0 && w[j] > k) { w[j + 1] = w[j]; j--; }
        w[j + 1] = k;
    }
    return 0.5f * (w[4] + w[5]);
}

__device__ inline bool outlier_flag(const float* w) {
    float med = median10(w);
    float d[10];
    #pragma unroll
    for (int i = 0; i < 10; i++) d[i] = fabsf(w[i] - med);
    float d0 = d[0];
    float mad = median10(d);
    return (0.6745f * d0 / mad) > 2.0f;
}

__device__ inline unsigned wave_sum_u32(unsigned v) {
    for (int off = 32; off; off >>= 1) v += __shfl_xor(v, off);
    return v;
}

// ============================================================================
// FUSED single cooperative kernel: all phases, grid.sync() between them.
// ============================================================================
__global__ __launch_bounds__(256, 2)
void fused_kernel(const float* __restrict__ events,
                  float* __restrict__ alongX,
                  float* __restrict__ alongY,
                  unsigned* __restrict__ compact,
                  unsigned* __restrict__ container,
                  unsigned long long* __restrict__ sums,
                  int* __restrict__ alignedX,
                  int* __restrict__ alignedY,
                  float* __restrict__ m_all,
                  unsigned* __restrict__ masks,
                  unsigned long long* __restrict__ commitmask,
                  float* __restrict__ out) {
    cg::grid_group grid = cg::this_grid();
    __shared__ float sbuf[NS * ND];                 // 48 KB master buffer
    __shared__ double sredA[4], sredB[4];
    __shared__ unsigned long long credA[4], credB[4];
    __shared__ float scv;
    int tid = threadIdx.x, blk = blockIdx.x;

    // ---- Phase 1: zero container/sums + histograms + compact stream -------
    {
        uint4 z = {0u, 0u, 0u, 0u};
        for (int i = blk * 256 + tid; i < 262144; i += GRID * 256)
            ((uint4*)container)[i] = z;
        if (blk == 0 && tid < NB * 2) sums[tid] = 0ull;

        unsigned (*hx)[ND] = (unsigned (*)[ND])sbuf;            // 4 KB
        unsigned (*hy)[ND] = (unsigned (*)[ND])(sbuf + 1024);   // 4 KB
        int wave = tid >> 6;
        for (int tile = blk; tile < NB * NS; tile += GRID) {
            __syncthreads();
            #pragma unroll
            for (int j = 0; j < 4; j++) { hx[j][tid] = 0; hy[j][tid] = 0; }
            __syncthreads();
            int b = tile / NS, c = tile % NS;
            size_t base = (size_t)b * NEV + (size_t)c * SEG;
            const float4* ev4 = (const float4*)(events + base * 2);
            bool wr = (c >= S_IDX && c < E_IDX);
            uint2* dst = wr ? (uint2*)(compact + ((size_t)b * NCH + (c - S_IDX)) * (SEG / 2)) : nullptr;
            unsigned* HX = hx[wave];
            unsigned* HY = hy[wave];
            for (int k = tid; k < SEG / 4; k += 256) {
                float4 v0 = ev4[2 * k], v1 = ev4[2 * k + 1];
                int x0 = (int)v0.x, y0 = (int)v0.y, x1 = (int)v0.z, y1 = (int)v0.w;
                int x2 = (int)v1.x, y2 = (int)v1.y, x3 = (int)v1.z, y3 = (int)v1.w;
                x0 = x0 > 255 ? 255 : x0; y0 = y0 > 255 ? 255 : y0;
                x1 = x1 > 255 ? 255 : x1; y1 = y1 > 255 ? 255 : y1;
                x2 = x2 > 255 ? 255 : x2; y2 = y2 > 255 ? 255 : y2;
                x3 = x3 > 255 ? 255 : x3; y3 = y3 > 255 ? 255 : y3;
                atomicAdd(&HX[x0], 1u); atomicAdd(&HY[y0], 1u);
                atomicAdd(&HX[x1], 1u); atomicAdd(&HY[y1], 1u);
                atomicAdd(&HX[x2], 1u); atomicAdd(&HY[y2], 1u);
                atomicAdd(&HX[x3], 1u); atomicAdd(&HY[y3], 1u);
                if (wr) {
                    uint2 p;
                    p.x = (unsigned)(x0 | (y0 << 8)) | ((unsigned)(x1 | (y1 << 8)) << 16);
                    p.y = (unsigned)(x2 | (y2 << 8)) | ((unsigned)(x3 | (y3 << 8)) << 16);
                    dst[k] = p;
                }
            }
            __syncthreads();
            unsigned sx = hx[0][tid] + hx[1][tid] + hx[2][tid] + hx[3][tid];
            unsigned sy = hy[0][tid] + hy[1][tid] + hy[2][tid] + hy[3][tid];
            int o = tile * ND + tid;
            alongX[o] = (float)sx;
            alongY[o] = (float)sy;
        }
    }
    grid.sync();

    // ---- Phase 2: stats (cv, blur-centroid m, aligned) — blocks 0..31 -----
    if (blk < NB * 2) {
        int b = blk >> 1, axis = blk & 1;
        const float* along = (axis ? alongY : alongX) + (size_t)b * NS * ND;
        for (int k = 0; k < NS; k++) sbuf[k * ND + tid] = along[k * ND + tid];
        __syncthreads();
        double s = 0.0, s2 = 0.0;
        for (int k = 0; k < NS; k++) { double v = sbuf[k * ND + tid]; s += v; s2 += v * v; }
        for (int off = 32; off; off >>= 1) { s += __shfl_down(s, off); s2 += __shfl_down(s2, off); }
        if ((tid & 63) == 0) { sredA[tid >> 6] = s; sredB[tid >> 6] = s2; }
        __syncthreads();
        if (tid == 0) {
            double ts = sredA[0] + sredA[1] + sredA[2] + sredA[3];
            double ts2 = sredB[0] + sredB[1] + sredB[2] + sredB[3];
            const double N = (double)(NS * ND);
            double mean = ts / N;
            double var  = (ts2 - ts * ts / N) / (N - 1.0);
            scv = (float)(mean + 3.0 * sqrt(var));
        }
        __syncthreads();
        float cv = scv;
        int wave = tid >> 6, lane = tid & 63;
        for (int q = 0; q < 12; ++q) {
            int sI = wave * 12 + q;
            double acc = 0.0;
            #pragma unroll
            for (int k = 0; k < 4; ++k) {
                int d = lane + 64 * k;
                int lo = d - 2 < 0 ? 0 : d - 2;
                int hi = d + 2 > 255 ? 255 : d + 2;
                double Wd = 0.5 * (double)(lo + hi) * (double)(hi - lo + 1);
                double t = 0.0;
                #pragma unroll
                for (int ds = -2; ds <= 2; ++ds) {
                    int ss = sI + ds;
                    if (ss >= 0 && ss < NS) t += (double)fminf(sbuf[ss * ND + d], cv);
                }
                acc += t * Wd;
            }
            for (int off = 32; off; off >>= 1) acc += __shfl_down(acc, off);
            if (lane == 0) {
                float mf = (float)(acc * 0.04 / (double)SEG);
                m_all[(b * 2 + axis) * NS + sI] = mf;
                // m - start - (128 - start) == m - 128 (Sterbenz-exact)
                (axis ? alignedY : alignedX)[b * NS + sI] = (int)rintf(mf - 128.0f);
            }
        }
    }
    grid.sync();

    // ---- Phase 3: per-(batch,chunk) half-res visit masks ------------------
    {
        unsigned* sm = (unsigned*)sbuf;                  // 2 KB
        for (int tile = blk; tile < NB * NCH; tile += GRID) {
            __syncthreads();
            sm[tid] = 0; sm[tid + 256] = 0;
            __syncthreads();
            int b = tile / NCH, ci = tile % NCH, si = S_IDX + ci;
            int aX = alignedX[b * NS + si], aY = alignedY[b * NS + si];
            const uint4* cp = (const uint4*)(compact + ((size_t)b * NCH + ci) * (SEG / 2));
            for (int i = tid; i < SEG / 8; i += 256) {
                uint4 w = cp[i];
                unsigned wsv[4] = {w.x, w.y, w.z, w.w};
                #pragma unroll
                for (int j = 0; j < 4; j++) {
                    unsigned v = wsv[j];
                    #pragma unroll
                    for (int h = 0; h < 2; h++) {
                        unsigned e = (h ? (v >> 16) : v) & 0xFFFFu;
                        int xs = (int)(e & 255u) - aX; xs = xs < 0 ? 0 : (xs > 255 ? 255 : xs);
                        int ys = (int)(e >> 8)   - aY; ys = ys < 0 ? 0 : (ys > 255 ? 255 : ys);
                        int iv = (xs >> 1) | ((ys >> 1) << 7);
                        atomicOr(&sm[iv >> 5], 1u << (iv & 31));
                    }
                }
            }
            __syncthreads();
            unsigned* mo = masks + (size_t)tile * 512;
            mo[tid] = sm[tid];
            mo[tid + 256] = sm[tid + 256];
        }
    }
    grid.sync();

    // ---- Phase 4: serial decision walk — wave 0 of blocks 0..15 -----------
    if (blk < NB && tid < 64) {
        int b = blk, lane = tid;
        const unsigned* mb = masks + (size_t)b * NCH * 512;
        uint4 v0 = ((const uint4*)mb)[lane * 2];
        uint4 v1 = ((const uint4*)mb)[lane * 2 + 1];
        const uint4* pp = (const uint4*)(mb + 512);
        uint4 p0 = pp[lane * 2], p1 = pp[lane * 2 + 1];
        bool f = false;
        if (lane < N_ITER) {
            const float* mx = m_all + b * 2 * NS;
            const float* my = mx + NS;
            f = outlier_flag(&mx[S_IDX + 1 + lane]) || outlier_flag(&my[S_IDX + 1 + lane]);
        }
        unsigned long long omask = __ballot(f);
        unsigned ver[8] = {v0.x, v0.y, v0.z, v0.w, v1.x, v1.y, v1.z, v1.w};
        unsigned pc = 0;
        #pragma unroll
        for (int j = 0; j < 8; j++) pc += __popc(ver[j]);
        unsigned cnt = wave_sum_u32(pc);
        unsigned long long cm = 1ull;          // chunk S_IDX always committed
        for (int idx = 1; idx < NCH; ++idx) {
            uint4 c0 = p0, c1 = p1;
            if (idx + 1 < NCH) {
                const uint4* np = (const uint4*)(mb + (size_t)(idx + 1) * 512);
                p0 = np[lane * 2]; p1 = np[lane * 2 + 1];
            }
            unsigned del[8] = {c0.x, c0.y, c0.z, c0.w, c1.x, c1.y, c1.z, c1.w};
            unsigned nl = 0;
            #pragma unroll
            for (int j = 0; j < 8; j++) nl += __popc(del[j] & ~ver[j]);
            unsigned ni = wave_sum_u32(nl);
            bool is_o = (omask >> (idx - 1)) & 1;
            if (!is_o) {
                unsigned cn = cnt + ni;
                float ratio = (float)ni / (float)cn;   // exact ints in f32 div
                if (ratio < 0.1f) break;
                cm |= 1ull << idx;
                cnt = cn;
                #pragma unroll
                for (int j = 0; j < 8; j++) ver[j] |= del[j];
            }
        }
        if (lane == 0) commitmask[b] = cm;
    }
    grid.sync();

    // ---- Phase 5: commit container for committed chunks -------------------
    for (int tile = blk; tile < NB * NCH; tile += GRID) {
        int b = tile / NCH, ci = tile % NCH;
        if (!((commitmask[b] >> ci) & 1ull)) continue;
        int si = S_IDX + ci;
        int aX = alignedX[b * NS + si], aY = alignedY[b * NS + si];
        unsigned* cont = container + (size_t)b * 65536;
        const uint4* cp = (const uint4*)(compact + ((size_t)b * NCH + ci) * (SEG / 2));
        for (int i = tid; i < SEG / 8; i += 256) {
            uint4 w = cp[i];
            unsigned wsv[4] = {w.x, w.y, w.z, w.w};
            #pragma unroll
            for (int j = 0; j < 4; j++) {
                unsigned v = wsv[j];
                #pragma unroll
                for (int h = 0; h < 2; h++) {
                    unsigned e = (h ? (v >> 16) : v) & 0xFFFFu;
                    int xs = (int)(e & 255u) - aX; xs = xs < 0 ? 0 : (xs > 255 ? 255 : xs);
                    int ys = (int)(e >> 8)   - aY; ys = ys < 0 ? 0 : (ys > 255 ? 255 : ys);
                    atomicAdd(&cont[xs | (ys << 8)], 1u);
                }
            }
        }
    }
    grid.sync();

    // ---- Phase 6: per-batch cv partials (exact u64) -----------------------
    if (blk < NB * 16) {
        int b = blk >> 4, part = blk & 15;
        const uint4* c4 = (const uint4*)(container + (size_t)b * 65536) + part * 1024;
        unsigned long long s = 0, s2 = 0;
        for (int i = tid; i < 1024; i += 256) {
            uint4 v = c4[i];
            s  += (unsigned long long)v.x + v.y + v.z + v.w;
            s2 += (unsigned long long)v.x * v.x + (unsigned long long)v.y * v.y
                + (unsigned long long)v.z * v.z + (unsigned long long)v.w * v.w;
        }
        for (int off = 32; off; off >>= 1) { s += __shfl_down(s, off); s2 += __shfl_down(s2, off); }
        if ((tid & 63) == 0) { credA[tid >> 6] = s; credB[tid >> 6] = s2; }
        __syncthreads();
        if (tid == 0) {
            atomicAdd(&sums[b * 2],     credA[0] + credA[1] + credA[2] + credA[3]);
            atomicAdd(&sums[b * 2 + 1], credB[0] + credB[1] + credB[2] + credB[3]);
        }
    }
    grid.sync();

    // ---- Phase 7: clip/normalize ------------------------------------------
    for (int g = blk * 256 + tid; g < 262144; g += GRID * 256) {
        int b = g >> 14;
        double ts  = (double)sums[b * 2];              // exact: < 2^53
        double ts2 = (double)sums[b * 2 + 1];
        double mean = ts / 65536.0;
        double var  = (ts2 - ts * ts / 65536.0) / 65535.0;
        float cv = (float)(mean + 3.0 * sqrt(var));
        uint4 v = ((const uint4*)container)[g];
        float4 o;
        o.x = fminf((float)v.x, cv) / cv;
        o.y = fminf((float)v.y, cv) / cv;
        o.z = fminf((float)v.z, cv) / cv;
        o.w = fminf((float)v.w, cv) / cv;
        ((float4*)out)[g] = o;
    }
}

// ============================================================================
// Fallback path: the proven 7-kernel pipeline (used only if cooperative
// occupancy is insufficient — same decision every call, graph-safe).
// ============================================================================
__global__ __launch_bounds__(256) void hist_kernel(const float* __restrict__ events,
                                                   float* __restrict__ alongX,
                                                   float* __restrict__ alongY,
                                                   unsigned* __restrict__ compact,
                                                   unsigned* __restrict__ container,
                                                   unsigned long long* __restrict__ sums) {
    __shared__ unsigned hx[4][ND], hy[4][ND];
    int tid = threadIdx.x;
    int blk = blockIdx.x;
    int b = blk / NS, c = blk % NS;
    int wave = tid >> 6;
    #pragma unroll
    for (int j = 0; j < 4; j++) { hx[j][tid] = 0; hy[j][tid] = 0; }
    {
        uint4 z = {0u, 0u, 0u, 0u};
        for (int i = blk * 256 + tid; i < 262144; i += NB * NS * 256)
            ((uint4*)container)[i] = z;
        if (blk == 0 && tid < NB * 2) sums[tid] = 0ull;
    }
    __syncthreads();
    size_t base = (size_t)b * NEV + (size_t)c * SEG;
    const float4* ev4 = (const float4*)(events + base * 2);
    bool wr = (c >= S_IDX && c < E_IDX);
    uint2* dst = wr ? (uint2*)(compact + ((size_t)b * NCH + (c - S_IDX)) * (SEG / 2)) : nullptr;
    unsigned* HX = hx[wave];
    unsigned* HY = hy[wave];
    for (int k = tid; k < SEG / 4; k += 256) {
        float4 v0 = ev4[2 * k], v1 = ev4[2 * k + 1];
        int x0 = (int)v0.x, y0 = (int)v0.y, x1 = (int)v0.z, y1 = (int)v0.w;
        int x2 = (int)v1.x, y2 = (int)v1.y, x3 = (int)v1.z, y3 = (int)v1.w;
        x0 = x0 > 255 ? 255 : x0; y0 = y0 > 255 ? 255 : y0;
        x1 = x1 > 255 ? 255 : x1; y1 = y1 > 255 ? 255 : y1;
        x2 = x2 > 255 ? 255 : x2; y2 = y2 > 255 ? 255 : y2;
        x3 = x3 > 255 ? 255 : x3; y3 = y3 > 255 ? 255 : y3;
        atomicAdd(&HX[x0], 1u); atomicAdd(&HY[y0], 1u);
        atomicAdd(&HX[x1], 1u); atomicAdd(&HY[y1], 1u);
        atomicAdd(&HX[x2], 1u); atomicAdd(&HY[y2], 1u);
        atomicAdd(&HX[x3], 1u); atomicAdd(&HY[y3], 1u);
        if (wr) {
            uint2 p;
            p.x = (unsigned)(x0 | (y0 << 8)) | ((unsigned)(x1 | (y1 << 8)) << 16);
            p.y = (unsigned)(x2 | (y2 << 8)) | ((unsigned)(x3 | (y3 << 8)) << 16);
            dst[k] = p;
        }
    }
    __syncthreads();
    unsigned sx = hx[0][tid] + hx[1][tid] + hx[2][tid] + hx[3][tid];
    unsigned sy = hy[0][tid] + hy[1][tid] + hy[2][tid] + hy[3][tid];
    int o = (b * NS + c) * ND + tid;
    alongX[o] = (float)sx;
    alongY[o] = (float)sy;
}

__global__ __launch_bounds__(256) void stats_kernel(const float* __restrict__ alongX,
                                                    const float* __restrict__ alongY,
                                                    int* __restrict__ alignedX,
                                                    int* __restrict__ alignedY,
                                                    float* __restrict__ m_all) {
    __shared__ float sbuf[NS * ND];
    __shared__ double sredA[4], sredB[4];
    __shared__ float scv;
    int tid = threadIdx.x;
    int b = blockIdx.x >> 1, axis = blockIdx.x & 1;
    const float* along = (axis ? alongY : alongX) + (size_t)b * NS * ND;
    for (int k = 0; k < NS; k++) sbuf[k * ND + tid] = along[k * ND + tid];
    __syncthreads();
    double s = 0.0, s2 = 0.0;
    for (int k = 0; k < NS; k++) { double v = sbuf[k * ND + tid]; s += v; s2 += v * v; }
    for (int off = 32; off; off >>= 1) { s += __shfl_down(s, off); s2 += __shfl_down(s2, off); }
    if ((tid & 63) == 0) { sredA[tid >> 6] = s; sredB[tid >> 6] = s2; }
    __syncthreads();
    if (tid == 0) {
        double ts = sredA[0] + sredA[1] + sredA[2] + sredA[3];
        double ts2 = sredB[0] + sredB[1] + sredB[2] + sredB[3];
        const double N = (double)(NS * ND);
        double mean = ts / N;
        double var  = (ts2 - ts * ts / N) / (N - 1.0);
        scv = (float)(mean + 3.0 * sqrt(var));
    }
    __syncthreads();
    float cv = scv;
    int wave = tid >> 6, lane = tid & 63;
    for (int q = 0; q < 12; ++q) {
        int sI = wave * 12 + q;
        double acc = 0.0;
        #pragma unroll
        for (int k = 0; k < 4; ++k) {
            int d = lane + 64 * k;
            int lo = d - 2 < 0 ? 0 : d - 2;
            int hi = d + 2 > 255 ? 255 : d + 2;
            double Wd = 0.5 * (double)(lo + hi) * (double)(hi - lo + 1);
            double t = 0.0;
            #pragma unroll
            for (int ds = -2; ds <= 2; ++ds) {
                int ss = sI + ds;
                if (ss >= 0 && ss < NS) t += (double)fminf(sbuf[ss * ND + d], cv);
            }
            acc += t * Wd;
        }
        for (int off = 32; off; off >>= 1) acc += __shfl_down(acc, off);
        if (lane == 0) {
            float mf = (float)(acc * 0.04 / (double)SEG);
            m_all[(b * 2 + axis) * NS + sI] = mf;
            (axis ? alignedY : alignedX)[b * NS + sI] = (int)rintf(mf - 128.0f);
        }
    }
}

__global__ __launch_bounds__(256) void mask_kernel(const unsigned* __restrict__ compact,
                                                   const int* __restrict__ alignedX,
                                                   const int* __restrict__ alignedY,
                                                   unsigned* __restrict__ masks) {
    __shared__ unsigned sm[512];
    int tid = threadIdx.x, blk = blockIdx.x;
    int b = blk / NCH, ci = blk % NCH, si = S_IDX + ci;
    sm[tid] = 0; sm[tid + 256] = 0;
    __syncthreads();
    int aX = alignedX[b * NS + si], aY = alignedY[b * NS + si];
    const uint4* cp = (const uint4*)(compact + ((size_t)b * NCH + ci) * (SEG / 2));
    for (int i = tid; i < SEG / 8; i += 256) {
        uint4 w = cp[i];
        unsigned wsv[4] = {w.x, w.y, w.z, w.w};
        #pragma unroll
        for (int j = 0; j < 4; j++) {
            unsigned v = wsv[j];
            #pragma unroll
            for (int h = 0; h < 2; h++) {
                unsigned e = (h ? (v >> 16) : v) & 0xFFFFu;
                int xs = (int)(e & 255u) - aX; xs = xs < 0 ? 0 : (xs > 255 ? 255 : xs);
                int ys = (int)(e >> 8)   - aY; ys = ys < 0 ? 0 : (ys > 255 ? 255 : ys);
                int iv = (xs >> 1) | ((ys >> 1) << 7);
                atomicOr(&sm[iv >> 5], 1u << (iv & 31));
            }
        }
    }
    __syncthreads();
    unsigned* mo = masks + (size_t)blk * 512;
    mo[tid] = sm[tid];
    mo[tid + 256] = sm[tid + 256];
}

__global__ __launch_bounds__(64) void decide_kernel(const unsigned* __restrict__ masks,
                                                    const float* __restrict__ m_all,
                                                    unsigned long long* __restrict__ commitmask) {
    int b = blockIdx.x, lane = threadIdx.x;
    const unsigned* mb = masks + (size_t)b * NCH * 512;
    uint4 v0 = ((const uint4*)mb)[lane * 2];
    uint4 v1 = ((const uint4*)mb)[lane * 2 + 1];
    const uint4* pp = (const uint4*)(mb + 512);
    uint4 p0 = pp[lane * 2], p1 = pp[lane * 2 + 1];
    bool f = false;
    if (lane < N_ITER) {
        const float* mx = m_all + b * 2 * NS;
        const float* my = mx + NS;
        f = outlier_flag(&mx[S_IDX + 1 + lane]) || outlier_flag(&my[S_IDX + 1 + lane]);
    }
    unsigned long long omask = __ballot(f);
    unsigned ver[8] = {v0.x, v0.y, v0.z, v0.w, v1.x, v1.y, v1.z, v1.w};
    unsigned pc = 0;
    #pragma unroll
    for (int j = 0; j < 8; j++) pc += __popc(ver[j]);
    unsigned cnt = wave_sum_u32(pc);
    unsigned long long cm = 1ull;
    for (int idx = 1; idx < NCH; ++idx) {
        uint4 c0 = p0, c1 = p1;
        if (idx + 1 < NCH) {
            const uint4* np = (const uint4*)(mb + (size_t)(idx + 1) * 512);
            p0 = np[lane * 2]; p1 = np[lane * 2 + 1];
        }
        unsigned del[8] = {c0.x, c0.y, c0.z, c0.w, c1.x, c1.y, c1.z, c1.w};
        unsigned nl = 0;
        #pragma unroll
        for (int j = 0; j < 8; j++) nl += __popc(del[j] & ~ver[j]);
        unsigned ni = wave_sum_u32(nl);
        bool is_o = (omask >> (idx - 1)) & 1;
        if (!is_o) {
            unsigned cn = cnt + ni;
            float ratio = (float)ni / (float)cn;
            if (ratio < 0.1f) break;
            cm |= 1ull << idx;
            cnt = cn;
            #pragma unroll
            for (int j = 0; j < 8; j++) ver[j] |= del[j];
        }
    }
    if (lane == 0) commitmask[b] = cm;
}

__global__ __launch_bounds__(256) void commit_kernel(const unsigned* __restrict__ compact,
                                                     const int* __restrict__ alignedX,
                                                     const int* __restrict__ alignedY,
                                                     const unsigned long long* __restrict__ commitmask,
                                                     unsigned* __restrict__ container) {
    int blk = blockIdx.x, tid = threadIdx.x;
    int b = blk / NCH, ci = blk % NCH;
    if (!((commitmask[b] >> ci) & 1ull)) return;
    int si = S_IDX + ci;
    int aX = alignedX[b * NS + si], aY = alignedY[b * NS + si];
    unsigned* cont = container + (size_t)b * 65536;
    const uint4* cp = (const uint4*)(compact + ((size_t)b * NCH + ci) * (SEG / 2));
    for (int i = tid; i < SEG / 8; i += 256) {
        uint4 w = cp[i];
        unsigned wsv[4] = {w.x, w.y, w.z, w.w};
        #pragma unroll
        for (int j = 0; j < 4; j++) {
            unsigned v = wsv[j];
            #pragma unroll
            for (int h = 0; h < 2; h++) {
                unsigned e = (h ? (v >> 16) : v) & 0xFFFFu;
                int xs = (int)(e & 255u) - aX; xs = xs < 0 ? 0 : (xs > 255 ? 255 : xs);
                int ys = (int)(e >> 8)   - aY; ys = ys < 0 ? 0 : (ys > 255 ? 255 : ys);
                atomicAdd(&cont[xs | (ys << 8)], 1u);
            }
        }
    }
}

__global__ __launch_bounds__(256) void cv_kernel(const unsigned* __restrict__ container,
                                                 unsigned long long* __restrict__ sums) {
    __shared__ unsigned long long sredA[4], sredB[4];
    int tid = threadIdx.x, blk = blockIdx.x;
    int b = blk >> 4, part = blk & 15;
    const uint4* c4 = (const uint4*)(container + (size_t)b * 65536) + part * 1024;
    unsigned long long s = 0, s2 = 0;
    for (int i = tid; i < 1024; i += 256) {
        uint4 v = c4[i];
        s  += (unsigned long long)v.x + v.y + v.z + v.w;
        s2 += (unsigned long long)v.x * v.x + (unsigned long long)v.y * v.y
            + (unsigned long long)v.z * v.z + (unsigned long long)v.w * v.w;
    }
    for (int off = 32; off; off >>= 1) { s += __shfl_down(s, off); s2 += __shfl_down(s2, off); }
    if ((tid & 63) == 0) { sredA[tid >> 6] = s; sredB[tid >> 6] = s2; }
    __syncthreads();
    if (tid == 0) {
        atomicAdd(&sums[b * 2],     sredA[0] + sredA[1] + sredA[2] + sredA[3]);
        atomicAdd(&sums[b * 2 + 1], sredB[0] + sredB[1] + sredB[2] + sredB[3]);
    }
}

__global__ __launch_bounds__(256) void finish_kernel(const unsigned* __restrict__ container,
                                                     const unsigned long long* __restrict__ sums,
                                                     float* __restrict__ out) {
    int g = blockIdx.x * 256 + threadIdx.x;
    int b = g >> 14;
    double ts  = (double)sums[b * 2];
    double ts2 = (double)sums[b * 2 + 1];
    double mean = ts / 65536.0;
    double var  = (ts2 - ts * ts / 65536.0) / 65535.0;
    float cv = (float)(mean + 3.0 * sqrt(var));
    uint4 v = ((const uint4*)container)[g];
    float4 o;
    o.x = fminf((float)v.x, cv) / cv;
    o.y = fminf((float)v.y, cv) / cv;
    o.z = fminf((float)v.z, cv) / cv;
    o.w = fminf((float)v.w, cv) / cv;
    ((float4*)out)[g] = o;
}

// ---------------- Launcher -------------------------------------------------
extern "C" void kernel_launch(void* const* d_in, const int* in_sizes, int n_in,
                              void* d_out, int out_size, void* d_ws, size_t ws_size,
                              hipStream_t stream) {
    const float* events = (const float*)d_in[0];
    float* out = (float*)d_out;
    char* ws = (char*)d_ws;

    float*    alongX    = (float*)(ws);
    float*    alongY    = (float*)(ws + 786432);
    unsigned* container = (unsigned*)(ws + 1572864);
    int*      alignedX  = (int*)(ws + 5767168);
    int*      alignedY  = (int*)(ws + 5770240);
    float*    m_all     = (float*)(ws + 5773312);
    unsigned long long* commitmask = (unsigned long long*)(ws + 5779456);
    unsigned long long* sums       = (unsigned long long*)(ws + 5779584);
    unsigned* compact   = (unsigned*)(ws + 6291456);
    unsigned* masks     = (unsigned*)(ws + 29360128);

    // Cooperative capacity check (same result every call — graph-safe).
    int maxBlocksPerCU = 0;
    hipError_t occ_err = hipOccupancyMaxActiveBlocksPerMultiprocessor(
        &maxBlocksPerCU, (const void*)fused_kernel, 256, 0);
    bool coop_ok = (occ_err == hipSuccess) && (maxBlocksPerCU * 256 >= GRID);

    if (coop_ok) {
        void* args[] = {(void*)&events, (void*)&alongX, (void*)&alongY, (void*)&compact,
                        (void*)&container, (void*)&sums, (void*)&alignedX, (void*)&alignedY,
                        (void*)&m_all, (void*)&masks, (void*)&commitmask, (void*)&out};
        hipLaunchCooperativeKernel((const void*)fused_kernel, dim3(GRID), dim3(256),
                                   args, 0, stream);
    } else {
        hist_kernel<<<NB * NS, 256, 0, stream>>>(events, alongX, alongY, compact, container, sums);
        stats_kernel<<<NB * 2, 256, 0, stream>>>(alongX, alongY, alignedX, alignedY, m_all);
        mask_kernel<<<NB * NCH, 256, 0, stream>>>(compact, alignedX, alignedY, masks);
        decide_kernel<<<NB, 64, 0, stream>>>(masks, m_all, commitmask);
        commit_kernel<<<NB * NCH, 256, 0, stream>>>(compact, alignedX, alignedY, commitmask, container);
        cv_kernel<<<NB * 16, 256, 0, stream>>>(container, sums);
        finish_kernel<<<1024, 256, 0, stream>>>(container, sums, out);
    }
}

// Round 7
// 269.559 us; speedup vs baseline: 2.1789x; 2.1789x over previous
//
#include <hip/hip_runtime.h>

#define NB 16
#define NEV 960000
#define NS 48
#define SEG 20000
#define S_IDX 3
#define E_IDX 38
#define N_ITER 34
#define ND 256
#define NCH 35          // chunks S_IDX .. E_IDX-1

// ---------------- Kernel 1: histograms + compact + zero + exact cv sums ----
// One block per (b,c). Per-wave privatized LDS histograms; 8 events/iter for
// deep VMEM pipelining; final bins are per-chunk-complete so Sum(n^2) per
// (b,axis) can be accumulated exactly in u64 (bit-identical cv downstream).
__global__ __launch_bounds__(256) void hist_kernel(const float* __restrict__ events,
                                                   float* __restrict__ alongX,
                                                   float* __restrict__ alongY,
                                                   unsigned* __restrict__ compact,
                                                   unsigned* __restrict__ container,
                                                   unsigned* __restrict__ masks,
                                                   unsigned long long* __restrict__ sums,
                                                   unsigned long long* __restrict__ cvsums) {
    __shared__ unsigned hx[4][ND], hy[4][ND];   // 8 KB
    __shared__ unsigned long long qredX[4], qredY[4];
    int tid = threadIdx.x;
    int blk = blockIdx.x;
    int b = blk / NS, c = blk % NS;
    int wave = tid >> 6, lane = tid & 63;
    #pragma unroll
    for (int j = 0; j < 4; j++) { hx[j][tid] = 0; hy[j][tid] = 0; }
    // zero-fold: container (4 MB) + masks (1.1 MB) + accumulators
    {
        uint4 z = {0u, 0u, 0u, 0u};
        for (int i = blk * 256 + tid; i < 262144; i += NB * NS * 256)
            ((uint4*)container)[i] = z;
        for (int i = blk * 256 + tid; i < 71680; i += NB * NS * 256)
            ((uint4*)masks)[i] = z;
        if (blk == 0 && tid < NB * 2) sums[tid] = 0ull;
        if (blk == 1 && tid < NB * 2) cvsums[tid] = 0ull;
    }
    __syncthreads();
    size_t base = (size_t)b * NEV + (size_t)c * SEG;
    const float4* ev4 = (const float4*)(events + base * 2);   // 2 events per float4
    bool wr = (c >= S_IDX && c < E_IDX);
    uint4* dst = wr ? (uint4*)(compact + ((size_t)b * NCH + (c - S_IDX)) * (SEG / 2)) : nullptr;
    unsigned* HX = hx[wave];
    unsigned* HY = hy[wave];
    for (int k = tid; k < SEG / 8; k += 256) {          // 2500 iters of 8 events
        float4 v0 = ev4[4 * k], v1 = ev4[4 * k + 1], v2 = ev4[4 * k + 2], v3 = ev4[4 * k + 3];
        int x0 = (int)v0.x, y0 = (int)v0.y, x1 = (int)v0.z, y1 = (int)v0.w;
        int x2 = (int)v1.x, y2 = (int)v1.y, x3 = (int)v1.z, y3 = (int)v1.w;
        int x4 = (int)v2.x, y4 = (int)v2.y, x5 = (int)v2.z, y5 = (int)v2.w;
        int x6 = (int)v3.x, y6 = (int)v3.y, x7 = (int)v3.z, y7 = (int)v3.w;
        x0 = x0 > 255 ? 255 : x0; y0 = y0 > 255 ? 255 : y0;
        x1 = x1 > 255 ? 255 : x1; y1 = y1 > 255 ? 255 : y1;
        x2 = x2 > 255 ? 255 : x2; y2 = y2 > 255 ? 255 : y2;
        x3 = x3 > 255 ? 255 : x3; y3 = y3 > 255 ? 255 : y3;
        x4 = x4 > 255 ? 255 : x4; y4 = y4 > 255 ? 255 : y4;
        x5 = x5 > 255 ? 255 : x5; y5 = y5 > 255 ? 255 : y5;
        x6 = x6 > 255 ? 255 : x6; y6 = y6 > 255 ? 255 : y6;
        x7 = x7 > 255 ? 255 : x7; y7 = y7 > 255 ? 255 : y7;
        atomicAdd(&HX[x0], 1u); atomicAdd(&HY[y0], 1u);
        atomicAdd(&HX[x1], 1u); atomicAdd(&HY[y1], 1u);
        atomicAdd(&HX[x2], 1u); atomicAdd(&HY[y2], 1u);
        atomicAdd(&HX[x3], 1u); atomicAdd(&HY[y3], 1u);
        atomicAdd(&HX[x4], 1u); atomicAdd(&HY[y4], 1u);
        atomicAdd(&HX[x5], 1u); atomicAdd(&HY[y5], 1u);
        atomicAdd(&HX[x6], 1u); atomicAdd(&HY[y6], 1u);
        atomicAdd(&HX[x7], 1u); atomicAdd(&HY[y7], 1u);
        if (wr) {
            uint4 p;
            p.x = (unsigned)(x0 | (y0 << 8)) | ((unsigned)(x1 | (y1 << 8)) << 16);
            p.y = (unsigned)(x2 | (y2 << 8)) | ((unsigned)(x3 | (y3 << 8)) << 16);
            p.z = (unsigned)(x4 | (y4 << 8)) | ((unsigned)(x5 | (y5 << 8)) << 16);
            p.w = (unsigned)(x6 | (y6 << 8)) | ((unsigned)(x7 | (y7 << 8)) << 16);
            dst[k] = p;
        }
    }
    __syncthreads();
    unsigned sx = hx[0][tid] + hx[1][tid] + hx[2][tid] + hx[3][tid];
    unsigned sy = hy[0][tid] + hy[1][tid] + hy[2][tid] + hy[3][tid];
    int o = (b * NS + c) * ND + tid;
    alongX[o] = (float)sx;
    alongY[o] = (float)sy;
    // exact Sum(n^2) per (b,axis): u64, order-independent, < 2^53 overall
    unsigned long long qx = (unsigned long long)sx * sx;
    unsigned long long qy = (unsigned long long)sy * sy;
    for (int off = 32; off; off >>= 1) { qx += __shfl_down(qx, off); qy += __shfl_down(qy, off); }
    if (lane == 0) { qredX[wave] = qx; qredY[wave] = qy; }
    __syncthreads();
    if (tid == 0) {
        atomicAdd(&cvsums[b * 2],     qredX[0] + qredX[1] + qredX[2] + qredX[3]);
        atomicAdd(&cvsums[b * 2 + 1], qredY[0] + qredY[1] + qredY[2] + qredY[3]);
    }
}

// ---------------- Kernel 2: blur-centroid m + aligned ----------------------
// One block per (b, axis, group-of-12-segments): 128 blocks. cv recomputed
// per-thread from the exact u64 sums (Sum(n) == 960000 is a constant).
__global__ __launch_bounds__(256) void stats_kernel(const float* __restrict__ alongX,
                                                    const float* __restrict__ alongY,
                                                    const unsigned long long* __restrict__ cvsums,
                                                    int* __restrict__ alignedX,
                                                    int* __restrict__ alignedY,
                                                    float* __restrict__ m_all) {
    __shared__ float sbuf[16 * ND];        // 16 KB: rows base..base+15
    int tid = threadIdx.x;
    int blk = blockIdx.x;
    int g = blk & 3, axis = (blk >> 2) & 1, b = blk >> 3;
    const float* along = (axis ? alongY : alongX) + (size_t)b * NS * ND;
    int rbase = g * 12 - 2;                // virtual row of sbuf[0]
    for (int j = 0; j < 16; j++) {
        int r = rbase + j;
        if (r >= 0 && r < NS) sbuf[j * ND + tid] = along[r * ND + tid];
    }
    double ts  = 960000.0;                 // Sum(n) = NS*SEG exactly
    double ts2 = (double)cvsums[b * 2 + axis];   // exact integer
    const double N = (double)(NS * ND);
    double mean = ts / N;
    double var  = (ts2 - ts * ts / N) / (N - 1.0);
    float cv = (float)(mean + 3.0 * sqrt(var));
    __syncthreads();
    int wave = tid >> 6, lane = tid & 63;
    // wave w handles segments g*12 + w*3 .. +2 (3 each); wave-local reductions
    for (int q = 0; q < 3; ++q) {
        int sI = g * 12 + wave * 3 + q;
        double acc = 0.0;
        #pragma unroll
        for (int k = 0; k < 4; ++k) {
            int d = lane + 64 * k;
            int lo = d - 2 < 0 ? 0 : d - 2;
            int hi = d + 2 > 255 ? 255 : d + 2;
            double Wd = 0.5 * (double)(lo + hi) * (double)(hi - lo + 1);
            double t = 0.0;
            #pragma unroll
            for (int ds = -2; ds <= 2; ++ds) {
                int ss = sI + ds;
                if (ss >= 0 && ss < NS) t += (double)fminf(sbuf[(ss - rbase) * ND + d], cv);
            }
            acc += t * Wd;
        }
        for (int off = 32; off; off >>= 1) acc += __shfl_down(acc, off);
        if (lane == 0) {
            float mf = (float)(acc * 0.04 / (double)SEG);
            m_all[(b * 2 + axis) * NS + sI] = mf;
            // m - start - (128 - start) == m - 128 (Sterbenz-exact)
            (axis ? alignedY : alignedX)[b * NS + sI] = (int)rintf(mf - 128.0f);
        }
    }
}

// ---------------- Kernel 3a: half-res visit masks (2 half-blocks/chunk) ----
__global__ __launch_bounds__(256) void mask_kernel(const unsigned* __restrict__ compact,
                                                   const int* __restrict__ alignedX,
                                                   const int* __restrict__ alignedY,
                                                   unsigned* __restrict__ masks) {
    __shared__ unsigned sm[512];
    int tid = threadIdx.x, blk = blockIdx.x;
    int hi = blk & 1;
    int tile = blk >> 1;
    int b = tile / NCH, ci = tile % NCH, si = S_IDX + ci;
    sm[tid] = 0; sm[tid + 256] = 0;
    __syncthreads();
    int aX = alignedX[b * NS + si], aY = alignedY[b * NS + si];
    const uint4* cp = (const uint4*)(compact + ((size_t)b * NCH + ci) * (SEG / 2));
    for (int i = hi * 1250 + tid; i < (hi + 1) * 1250; i += 256) {   // 2500 uint4 total
        uint4 w = cp[i];
        unsigned wsv[4] = {w.x, w.y, w.z, w.w};
        #pragma unroll
        for (int j = 0; j < 4; j++) {
            unsigned v = wsv[j];
            #pragma unroll
            for (int h = 0; h < 2; h++) {
                unsigned e = (h ? (v >> 16) : v) & 0xFFFFu;
                int xs = (int)(e & 255u) - aX; xs = xs < 0 ? 0 : (xs > 255 ? 255 : xs);
                int ys = (int)(e >> 8)   - aY; ys = ys < 0 ? 0 : (ys > 255 ? 255 : ys);
                int iv = (xs >> 1) | ((ys >> 1) << 7);
                atomicOr(&sm[iv >> 5], 1u << (iv & 31));
            }
        }
    }
    __syncthreads();
    unsigned* mo = masks + (size_t)tile * 512;   // zeroed in hist
    unsigned v0 = sm[tid], v1 = sm[tid + 256];
    if (v0) atomicOr(&mo[tid], v0);
    if (v1) atomicOr(&mo[tid + 256], v1);
}

// ---------------- outlier helpers ------------------------------------------
__device__ inline float median10(const float* v) {
    float w[10];
    #pragma unroll
    for (int i = 0; i < 10; i++) w[i] = v[i];
    #pragma unroll
    for (int i = 1; i < 10; i++) {
        float k = w[i]; int j = i - 1;
        while (j >= 0 && w[j] > k) { w[j + 1] = w[j]; j--; }
        w[j + 1] = k;
    }
    return 0.5f * (w[4] + w[5]);
}

__device__ inline bool outlier_flag(const float* w) {
    float med = median10(w);
    float d[10];
    #pragma unroll
    for (int i = 0; i < 10; i++) d[i] = fabsf(w[i] - med);
    float d0 = d[0];
    float mad = median10(d);
    return (0.6745f * d0 / mad) > 2.0f;
}

// ---------------- Kernel 3b: serial decision walk (1 wave / batch) ---------
__device__ inline unsigned wave_sum_u32(unsigned v) {
    for (int off = 32; off; off >>= 1) v += __shfl_xor(v, off);
    return v;
}

__global__ __launch_bounds__(64) void decide_kernel(const unsigned* __restrict__ masks,
                                                    const float* __restrict__ m_all,
                                                    unsigned long long* __restrict__ commitmask) {
    int b = blockIdx.x, lane = threadIdx.x;
    const unsigned* mb = masks + (size_t)b * NCH * 512;
    // ver: 8 words/lane, loaded as 2x uint4
    uint4 v0 = ((const uint4*)mb)[lane * 2];
    uint4 v1 = ((const uint4*)mb)[lane * 2 + 1];
    // prefetch chunk idx=1
    const uint4* pp = (const uint4*)(mb + 512);
    uint4 p0 = pp[lane * 2], p1 = pp[lane * 2 + 1];
    // outlier flags (lanes 0..33) while loads are in flight
    bool f = false;
    if (lane < N_ITER) {
        const float* mx = m_all + b * 2 * NS;
        const float* my = mx + NS;
        f = outlier_flag(&mx[S_IDX + 1 + lane]) || outlier_flag(&my[S_IDX + 1 + lane]);
    }
    unsigned long long omask = __ballot(f);
    unsigned ver[8] = {v0.x, v0.y, v0.z, v0.w, v1.x, v1.y, v1.z, v1.w};
    unsigned pc = 0;
    #pragma unroll
    for (int j = 0; j < 8; j++) pc += __popc(ver[j]);
    unsigned cnt = wave_sum_u32(pc);
    unsigned long long cm = 1ull;          // chunk S_IDX always committed
    for (int idx = 1; idx < NCH; ++idx) {
        uint4 c0 = p0, c1 = p1;
        if (idx + 1 < NCH) {
            const uint4* np = (const uint4*)(mb + (size_t)(idx + 1) * 512);
            p0 = np[lane * 2]; p1 = np[lane * 2 + 1];
        }
        unsigned del[8] = {c0.x, c0.y, c0.z, c0.w, c1.x, c1.y, c1.z, c1.w};
        unsigned nl = 0;
        #pragma unroll
        for (int j = 0; j < 8; j++) nl += __popc(del[j] & ~ver[j]);
        unsigned ni = wave_sum_u32(nl);
        bool is_o = (omask >> (idx - 1)) & 1;
        if (!is_o) {
            unsigned cn = cnt + ni;
            float ratio = (float)ni / (float)cn;   // exact ints in f32 div — matches jax
            if (ratio < 0.1f) break;
            cm |= 1ull << idx;
            cnt = cn;
            #pragma unroll
            for (int j = 0; j < 8; j++) ver[j] |= del[j];
        }
    }
    if (lane == 0) commitmask[b] = cm;
}

// ---------------- Kernel 3c: commit (4 quarter-blocks / chunk) -------------
__global__ __launch_bounds__(256) void commit_kernel(const unsigned* __restrict__ compact,
                                                     const int* __restrict__ alignedX,
                                                     const int* __restrict__ alignedY,
                                                     const unsigned long long* __restrict__ commitmask,
                                                     unsigned* __restrict__ container) {
    int blk = blockIdx.x, tid = threadIdx.x;
    int qi = blk & 3;
    int tile = blk >> 2;
    int b = tile / NCH, ci = tile % NCH;
    if (!((commitmask[b] >> ci) & 1ull)) return;
    int si = S_IDX + ci;
    int aX = alignedX[b * NS + si], aY = alignedY[b * NS + si];
    unsigned* cont = container + (size_t)b * 65536;
    const uint4* cp = (const uint4*)(compact + ((size_t)b * NCH + ci) * (SEG / 2));
    for (int i = qi * 625 + tid; i < (qi + 1) * 625; i += 256) {     // 2500 uint4 total
        uint4 w = cp[i];
        unsigned wsv[4] = {w.x, w.y, w.z, w.w};
        #pragma unroll
        for (int j = 0; j < 4; j++) {
            unsigned v = wsv[j];
            #pragma unroll
            for (int h = 0; h < 2; h++) {
                unsigned e = (h ? (v >> 16) : v) & 0xFFFFu;
                int xs = (int)(e & 255u) - aX; xs = xs < 0 ? 0 : (xs > 255 ? 255 : xs);
                int ys = (int)(e >> 8)   - aY; ys = ys < 0 ? 0 : (ys > 255 ? 255 : ys);
                atomicAdd(&cont[xs | (ys << 8)], 1u);
            }
        }
    }
}

// ---------------- Kernel 4a: per-batch cv partials (exact u64) -------------
__global__ __launch_bounds__(256) void cv_kernel(const unsigned* __restrict__ container,
                                                 unsigned long long* __restrict__ sums) {
    __shared__ unsigned long long sredA[4], sredB[4];
    int tid = threadIdx.x, blk = blockIdx.x;
    int b = blk >> 4, part = blk & 15;
    const uint4* c4 = (const uint4*)(container + (size_t)b * 65536) + part * 1024;
    unsigned long long s = 0, s2 = 0;
    for (int i = tid; i < 1024; i += 256) {
        uint4 v = c4[i];
        s  += (unsigned long long)v.x + v.y + v.z + v.w;
        s2 += (unsigned long long)v.x * v.x + (unsigned long long)v.y * v.y
            + (unsigned long long)v.z * v.z + (unsigned long long)v.w * v.w;
    }
    for (int off = 32; off; off >>= 1) { s += __shfl_down(s, off); s2 += __shfl_down(s2, off); }
    if ((tid & 63) == 0) { sredA[tid >> 6] = s; sredB[tid >> 6] = s2; }
    __syncthreads();
    if (tid == 0) {
        atomicAdd(&sums[b * 2],     sredA[0] + sredA[1] + sredA[2] + sredA[3]);
        atomicAdd(&sums[b * 2 + 1], sredB[0] + sredB[1] + sredB[2] + sredB[3]);
    }
}

// ---------------- Kernel 4b: clip/normalize --------------------------------
__global__ __launch_bounds__(256) void finish_kernel(const unsigned* __restrict__ container,
                                                     const unsigned long long* __restrict__ sums,
                                                     float* __restrict__ out) {
    int g = blockIdx.x * 256 + threadIdx.x;        // vec4 index, 262144 total
    int b = g >> 14;                               // 16384 vec4 per batch
    double ts  = (double)sums[b * 2];              // exact: < 2^53
    double ts2 = (double)sums[b * 2 + 1];
    double mean = ts / 65536.0;
    double var  = (ts2 - ts * ts / 65536.0) / 65535.0;
    float cv = (float)(mean + 3.0 * sqrt(var));
    uint4 v = ((const uint4*)container)[g];
    float4 o;
    o.x = fminf((float)v.x, cv) / cv;
    o.y = fminf((float)v.y, cv) / cv;
    o.z = fminf((float)v.z, cv) / cv;
    o.w = fminf((float)v.w, cv) / cv;
    ((float4*)out)[g] = o;
}

// ---------------- Launcher -------------------------------------------------
extern "C" void kernel_launch(void* const* d_in, const int* in_sizes, int n_in,
                              void* d_out, int out_size, void* d_ws, size_t ws_size,
                              hipStream_t stream) {
    const float* events = (const float*)d_in[0];
    float* out = (float*)d_out;
    char* ws = (char*)d_ws;

    // workspace layout (bytes):
    //   alongX  [16*48*256 f32] @ 0        (786432)
    //   alongY  [16*48*256 f32] @ 786432   (786432)
    //   container[16*65536 u32] @ 1572864  (4194304)
    //   alignedX [16*48 i32]    @ 5767168  (3072)
    //   alignedY [16*48 i32]    @ 5770240  (3072)
    //   m_all   [16*2*48 f32]   @ 5773312  (6144)
    //   commitmask [16 u64]     @ 5779456  (128)
    //   sums    [16*2 u64]      @ 5779584  (256)
    //   cvsums  [16*2 u64]      @ 5779840  (256)
    //   compact [16*35*10000 u32] @ 6291456 (22400000)
    //   masks   [16*35*512 u32] @ 29360128 (1146880)
    float*    alongX    = (float*)(ws);
    float*    alongY    = (float*)(ws + 786432);
    unsigned* container = (unsigned*)(ws + 1572864);
    int*      alignedX  = (int*)(ws + 5767168);
    int*      alignedY  = (int*)(ws + 5770240);
    float*    m_all     = (float*)(ws + 5773312);
    unsigned long long* commitmask = (unsigned long long*)(ws + 5779456);
    unsigned long long* sums       = (unsigned long long*)(ws + 5779584);
    unsigned long long* cvsums     = (unsigned long long*)(ws + 5779840);
    unsigned* compact   = (unsigned*)(ws + 6291456);
    unsigned* masks     = (unsigned*)(ws + 29360128);

    hist_kernel<<<NB * NS, 256, 0, stream>>>(events, alongX, alongY, compact,
                                             container, masks, sums, cvsums);
    stats_kernel<<<NB * 2 * 4, 256, 0, stream>>>(alongX, alongY, cvsums,
                                                 alignedX, alignedY, m_all);
    mask_kernel<<<NB * NCH * 2, 256, 0, stream>>>(compact, alignedX, alignedY, masks);
    decide_kernel<<<NB, 64, 0, stream>>>(masks, m_all, commitmask);
    commit_kernel<<<NB * NCH * 4, 256, 0, stream>>>(compact, alignedX, alignedY,
                                                    commitmask, container);
    cv_kernel<<<NB * 16, 256, 0, stream>>>(container, sums);
    finish_kernel<<<1024, 256, 0, stream>>>(container, sums, out);
}